// Round 10
// baseline (191.495 us; speedup 1.0000x reference)
//
#include <hip/hip_runtime.h>
#include <hip/hip_bf16.h>
#include <math.h>

#define T_ 128
#define B_ 32
#define V_ 32000
#define E_ 32
#define H_ 16
#define NSEG 20         // column segments
#define SEGW 1600       // V/NSEG
#define NIT 25          // SEGW/64 (four 16-col MFMA tiles per iteration)

typedef __attribute__((ext_vector_type(8))) short short8;  // bf16x8 MFMA fragment
typedef __attribute__((ext_vector_type(4))) float f32x4;

// MFMA with bias as the C operand: D = A*B + C, C[q] = bias[col q] (row-indep).
#define MFMA_BF16C(A, B, C) __builtin_amdgcn_mfma_f32_16x16x32_bf16((A), (B), (C), 0, 0, 0)

__device__ __forceinline__ float expsum4(f32x4 lg) {
    return (__expf(lg[0]) + __expf(lg[1])) + (__expf(lg[2]) + __expf(lg[3]));
}

// ws layout (float units):
//   xw         [2][T][B][H] f32      @ 0       (131072)
//   featsB     [4096][32]   bf16     @ 131072  (65536)
//   W_hoT      [32000][32]  bf16     @ 196608  (512000)
//   stats_part [4096][20]   f32      @ 708608  (81920)

// Kernel 0: xw[dir][t][b][j] = b_ih[j] + emb[ix[t][b]] @ W[0:E, j]
__global__ __launch_bounds__(256) void xw_kernel(const int* __restrict__ ix,
                                                 const float* __restrict__ emb,
                                                 const float* __restrict__ W_lr,
                                                 const float* __restrict__ b_lr,
                                                 const float* __restrict__ W_rl,
                                                 const float* __restrict__ b_rl,
                                                 float* __restrict__ xw) {
    int idx = blockIdx.x * 256 + threadIdx.x;          // 131072 total
    int j = idx & 15;
    int b = (idx >> 4) & 31;
    int t = (idx >> 9) & 127;
    int dir = idx >> 16;
    const float* W    = dir ? W_rl : W_lr;
    const float* bias = dir ? b_rl : b_lr;
    int tok = ix[t * B_ + b];
    const float* er = emb + (long)tok * E_;
    float acc = bias[j];
#pragma unroll
    for (int e = 0; e < E_; ++e) acc += er[e] * W[e * H_ + j];
    xw[idx] = acc;
}

// Kernel 1 (fused): blocks 0..15 = scan chains (1 wave each, 4 chains/wave);
// blocks 16..515 = W_ho transpose to bf16.
__global__ __launch_bounds__(64) void scanwt_kernel(const float* __restrict__ xw,
                                                    const float* __restrict__ W_lr,
                                                    const float* __restrict__ W_rl,
                                                    const float* __restrict__ h0p,
                                                    const float* __restrict__ mask_lr,
                                                    const float* __restrict__ mask_rl,
                                                    __hip_bfloat16* __restrict__ featsB,
                                                    const float* __restrict__ W_ho,
                                                    __hip_bfloat16* __restrict__ W_hoT) {
    if (blockIdx.x >= 16) {
        int c = (blockIdx.x - 16) * 64 + threadIdx.x;   // 500*64 = 32000 exactly
        __hip_bfloat16 tmp[32];
#pragma unroll
        for (int k = 0; k < 32; ++k) tmp[k] = __float2bfloat16(W_ho[k * V_ + c]);
        short8* dst = (short8*)(W_hoT + c * 32);
        const short8* src = (const short8*)tmp;
#pragma unroll
        for (int q = 0; q < 4; ++q) dst[q] = src[q];
        return;
    }
    int lane = threadIdx.x;
    int dir = blockIdx.x >> 3;
    int j = lane & 15;
    int b = (blockIdx.x & 7) * 4 + (lane >> 4);
    int bi = b * 16 + j;
    int base = lane & 48;
    const float* W    = dir ? W_rl : W_lr;
    const float* mask = dir ? mask_rl : mask_lr;
    const float* xwd  = xw + dir * (T_ * B_ * H_);
    float Wh[16];
#pragma unroll
    for (int k = 0; k < 16; ++k) Wh[k] = W[(E_ + k) * H_ + j];
    float h = h0p[j];
    if (dir == 0) featsB[(0 * B_ + b) * 32 + j] = __float2bfloat16(h);
    else          featsB[((T_ - 1) * B_ + b) * 32 + 16 + j] = __float2bfloat16(h);

    float x0[4], m0[4], x1[4], m1[4];
#define LOADCH(XB, MB, CH)                                                 \
    _Pragma("unroll")                                                      \
    for (int u = 0; u < 4; ++u) {                                          \
        int t = (CH) * 4 + u;                                              \
        int tt = dir ? (T_ - 1 - t) : t;                                   \
        XB[u] = xwd[tt * (B_ * H_) + bi];                                  \
        MB[u] = mask[tt * (B_ * H_) + bi];                                 \
    }
#define STEPS(XB, MB, CH)                                                  \
    _Pragma("unroll")                                                      \
    for (int u = 0; u < 4; ++u) {                                          \
        int t = (CH) * 4 + u;                                              \
        float a0 = XB[u], a1 = 0.f, a2 = 0.f, a3 = 0.f;                    \
        _Pragma("unroll")                                                  \
        for (int k = 0; k < 16; k += 4) {                                  \
            a0 += __shfl(h, base + k,     64) * Wh[k];                     \
            a1 += __shfl(h, base + k + 1, 64) * Wh[k + 1];                 \
            a2 += __shfl(h, base + k + 2, 64) * Wh[k + 2];                 \
            a3 += __shfl(h, base + k + 3, 64) * Wh[k + 3];                 \
        }                                                                  \
        float ax = (a0 + a1) + (a2 + a3);                                  \
        float ex = __expf(2.f * ax);                                       \
        float th = 1.f - 2.f * __builtin_amdgcn_rcpf(ex + 1.f);            \
        float hn = th * MB[u];                                             \
        h = hn;                                                            \
        int p = dir ? (T_ - 2 - t) : (t + 1);                              \
        if (p >= 0 && p < T_)                                              \
            featsB[(p * B_ + b) * 32 + dir * 16 + j] = __float2bfloat16(hn); \
    }
    LOADCH(x0, m0, 0)
#pragma unroll 1
    for (int c = 0; c < 32; c += 2) {
        if (c + 1 < 32) { LOADCH(x1, m1, c + 1) }
        STEPS(x0, m0, c)
        if (c + 2 < 32) { LOADCH(x0, m0, c + 2) }
        STEPS(x1, m1, c + 1)
    }
#undef LOADCH
#undef STEPS
}

// MFMA (16x16x32, swapped: A = W-tile [16 cols x 32 k], B = feats):
//   lane L: p = L&15, kb = (L>>4)*8; D: lane holds row (L&15), cols c0+(L>>4)*4+{0..3}

#define LDA4(d0, d1, d2, d3, itv)                                          \
    d0 = *(const short8*)(WA + (cbase + (itv) * 64 +  0 + p) * 32 + kb);   \
    d1 = *(const short8*)(WA + (cbase + (itv) * 64 + 16 + p) * 32 + kb);   \
    d2 = *(const short8*)(WA + (cbase + (itv) * 64 + 32 + p) * 32 + kb);   \
    d3 = *(const short8*)(WA + (cbase + (itv) * 64 + 48 + p) * 32 + kb);
#define LDB4(d0, d1, d2, d3, itv)                                          \
    d0 = *(const f32x4*)(b_ho + cbase + (itv) * 64 +  0 + quad);           \
    d1 = *(const f32x4*)(b_ho + cbase + (itv) * 64 + 16 + quad);           \
    d2 = *(const f32x4*)(b_ho + cbase + (itv) * 64 + 32 + quad);           \
    d3 = *(const f32x4*)(b_ho + cbase + (itv) * 64 + 48 + quad);

// Kernel 2: per-row sum(exp(logit)). Wave = 16 rows x one 1600-col segment
// (grid 1280 blocks -> 5 waves/SIMD for latency hiding). Depth-2 register
// pipeline; bias enters through the MFMA C operand (no VALU adds).
__global__ __launch_bounds__(256) void stats_kernel(const __hip_bfloat16* __restrict__ featsB,
                                                    const __hip_bfloat16* __restrict__ W_hoT,
                                                    const float* __restrict__ b_ho,
                                                    float* __restrict__ stats_part) {
    int wv = threadIdx.x >> 6, lane = threadIdx.x & 63;
    int rt = blockIdx.x * 4 + wv;        // 0..255 (16-row tiles)
    int seg = blockIdx.y;                // 0..19
    int row0 = rt * 16;
    int p = lane & 15, kb = (lane >> 4) * 8, quad = (lane >> 4) << 2;
    short8 bfrag = *(const short8*)((const short*)featsB + (row0 + p) * 32 + kb);
    int cbase = seg * SEGW;
    const short* WA = (const short*)W_hoT;
    short8 pa0, pa1, pa2, pa3, pb0, pb1, pb2, pb3;
    f32x4  ba0, ba1, ba2, ba3, bb0, bb1, bb2, bb3;
    LDA4(pa0, pa1, pa2, pa3, 0)
    LDB4(ba0, ba1, ba2, ba3, 0)
    LDA4(pb0, pb1, pb2, pb3, 1)
    LDB4(bb0, bb1, bb2, bb3, 1)
    float racc = 0.f;
#define SBODY(c0, c1, c2, c3, d0, d1, d2, d3)                              \
    racc += expsum4(MFMA_BF16C(c0, bfrag, d0));                            \
    racc += expsum4(MFMA_BF16C(c1, bfrag, d1));                            \
    racc += expsum4(MFMA_BF16C(c2, bfrag, d2));                            \
    racc += expsum4(MFMA_BF16C(c3, bfrag, d3));
#pragma unroll 1
    for (int it = 0; it < NIT; it += 2) {
        short8 c0 = pa0, c1 = pa1, c2 = pa2, c3 = pa3;
        f32x4  d0 = ba0, d1 = ba1, d2 = ba2, d3 = ba3;
        if (it + 2 < NIT) { LDA4(pa0, pa1, pa2, pa3, it + 2) LDB4(ba0, ba1, ba2, ba3, it + 2) }
        SBODY(c0, c1, c2, c3, d0, d1, d2, d3)
        if (it + 1 < NIT) {
            short8 e0 = pb0, e1 = pb1, e2 = pb2, e3 = pb3;
            f32x4  f0 = bb0, f1 = bb1, f2 = bb2, f3 = bb3;
            if (it + 3 < NIT) { LDA4(pb0, pb1, pb2, pb3, it + 3) LDB4(bb0, bb1, bb2, bb3, it + 3) }
            SBODY(e0, e1, e2, e3, f0, f1, f2, f3)
        }
    }
#undef SBODY
    racc += __shfl_xor(racc, 16, 64);
    racc += __shfl_xor(racc, 32, 64);
    if (lane < 16) stats_part[(row0 + lane) * NSEG + seg] = racc;
}

// Kernel 3: out = logit - lse. lse from stats_part in-prologue; biases in LDS
// (C operand from LDS load); depth-2 afrag pipeline; staged LDS transpose ->
// 256 B contiguous NT stores.
__global__ __launch_bounds__(256) void out_kernel(const __hip_bfloat16* __restrict__ featsB,
                                                  const __hip_bfloat16* __restrict__ W_hoT,
                                                  const float* __restrict__ b_ho,
                                                  const float* __restrict__ stats_part,
                                                  float* __restrict__ out) {
    __shared__ float tile[4][16][68];
    __shared__ float bseg[SEGW];
    int wv = threadIdx.x >> 6, lane = threadIdx.x & 63;
    int rt = blockIdx.x * 4 + wv;        // 0..255
    int seg = blockIdx.y;                // 0..19
    int row0 = rt * 16;
    int p = lane & 15, kb = (lane >> 4) * 8, quad = (lane >> 4) << 2;
    int cbase = seg * SEGW;
    for (int i = threadIdx.x; i < SEGW / 4; i += 256)
        *(f32x4*)(bseg + i * 4) = *(const f32x4*)(b_ho + cbase + i * 4);
    // lse for this lane's row: 5 x f32x4 over the 20 partials
    const f32x4* sp4 = (const f32x4*)(stats_part + (row0 + p) * NSEG);
    f32x4 s4 = sp4[0] + sp4[1] + sp4[2] + sp4[3] + sp4[4];
    float ls = __logf((s4[0] + s4[1]) + (s4[2] + s4[3]));
    short8 bfrag = *(const short8*)((const short*)featsB + (row0 + p) * 32 + kb);
    const short* WA = (const short*)W_hoT;
    float* tw = &tile[wv][0][0];
    int rr = lane >> 4;             // 0..3
    int cc = (lane & 15) * 4;       // 0..60
    short8 pa0, pa1, pa2, pa3, pb0, pb1, pb2, pb3;
    LDA4(pa0, pa1, pa2, pa3, 0)
    LDA4(pb0, pb1, pb2, pb3, 1)
    __syncthreads();                // bseg ready
#define OBODY(itv, c0, c1, c2, c3)                                          \
    {                                                                       \
        int co = (itv) * 64;                                                \
        f32x4 b40 = *(const f32x4*)(bseg + co +  0 + quad);                 \
        f32x4 b41 = *(const f32x4*)(bseg + co + 16 + quad);                 \
        f32x4 b42 = *(const f32x4*)(bseg + co + 32 + quad);                 \
        f32x4 b43 = *(const f32x4*)(bseg + co + 48 + quad);                 \
        f32x4 lg0 = MFMA_BF16C(c0, bfrag, b40);                             \
        f32x4 lg1 = MFMA_BF16C(c1, bfrag, b41);                             \
        f32x4 lg2 = MFMA_BF16C(c2, bfrag, b42);                             \
        f32x4 lg3 = MFMA_BF16C(c3, bfrag, b43);                             \
        *(f32x4*)(tw + p * 68 +  0 + quad) = lg0 - ls;                      \
        *(f32x4*)(tw + p * 68 + 16 + quad) = lg1 - ls;                      \
        *(f32x4*)(tw + p * 68 + 32 + quad) = lg2 - ls;                      \
        *(f32x4*)(tw + p * 68 + 48 + quad) = lg3 - ls;                      \
        int c0g = cbase + co;                                               \
        _Pragma("unroll")                                                   \
        for (int sN = 0; sN < 4; ++sN) {                                    \
            int r = sN * 4 + rr;                                            \
            f32x4 v = *(const f32x4*)(tw + r * 68 + cc);                    \
            __builtin_nontemporal_store(v, (f32x4*)(out + (long)(row0 + r) * V_ + c0g + cc)); \
        }                                                                   \
    }
#pragma unroll 1
    for (int it = 0; it < NIT; it += 2) {
        short8 c0 = pa0, c1 = pa1, c2 = pa2, c3 = pa3;
        if (it + 2 < NIT) { LDA4(pa0, pa1, pa2, pa3, it + 2) }
        OBODY(it, c0, c1, c2, c3)
        if (it + 1 < NIT) {
            short8 e0 = pb0, e1 = pb1, e2 = pb2, e3 = pb3;
            if (it + 3 < NIT) { LDA4(pb0, pb1, pb2, pb3, it + 3) }
            OBODY(it + 1, e0, e1, e2, e3)
        }
    }
#undef OBODY
}

extern "C" void kernel_launch(void* const* d_in, const int* in_sizes, int n_in,
                              void* d_out, int out_size, void* d_ws, size_t ws_size,
                              hipStream_t stream) {
    const int*   ix      = (const int*)d_in[0];
    const float* emb     = (const float*)d_in[1];
    const float* W_lr    = (const float*)d_in[2];
    const float* b_lr    = (const float*)d_in[3];
    const float* W_rl    = (const float*)d_in[4];
    const float* b_rl    = (const float*)d_in[5];
    const float* W_ho    = (const float*)d_in[6];
    const float* b_ho    = (const float*)d_in[7];
    const float* h0      = (const float*)d_in[8];
    const float* mask_lr = (const float*)d_in[9];
    const float* mask_rl = (const float*)d_in[10];
    float* out = (float*)d_out;
    float* ws  = (float*)d_ws;

    float*           xw         = ws;                                   // 131072
    __hip_bfloat16*  featsB     = (__hip_bfloat16*)(ws + 131072);       // 65536
    __hip_bfloat16*  W_hoT      = (__hip_bfloat16*)(ws + 196608);       // 512000
    float*           stats_part = ws + 708608;                          // 81920

    xw_kernel<<<512, 256, 0, stream>>>(ix, emb, W_lr, b_lr, W_rl, b_rl, xw);
    scanwt_kernel<<<516, 64, 0, stream>>>(xw, W_lr, W_rl, h0, mask_lr, mask_rl,
                                          featsB, W_ho, W_hoT);
    stats_kernel<<<dim3(64, NSEG), 256, 0, stream>>>(featsB, W_hoT, b_ho, stats_part);
    out_kernel<<<dim3(64, NSEG), 256, 0, stream>>>(featsB, W_hoT, b_ho, stats_part, out);
}

// Round 11
// 178.466 us; speedup vs baseline: 1.0730x; 1.0730x over previous
//
#include <hip/hip_runtime.h>
#include <hip/hip_bf16.h>
#include <math.h>

#define T_ 128
#define B_ 32
#define V_ 32000
#define E_ 32
#define H_ 16
#define NSEG 20         // column segments
#define SEGW 1600       // V/NSEG
#define NIT 25          // SEGW/64 (four 16-col MFMA tiles per iteration)

typedef __attribute__((ext_vector_type(8))) short short8;  // bf16x8 MFMA fragment
typedef __attribute__((ext_vector_type(4))) float f32x4;

// MFMA with bias as the C operand: D = A*B + C, C[q] = bias[col q] (row-indep).
#define MFMA_BF16C(A, B, C) __builtin_amdgcn_mfma_f32_16x16x32_bf16((A), (B), (C), 0, 0, 0)

__device__ __forceinline__ float expsum4(f32x4 lg) {
    return (__expf(lg[0]) + __expf(lg[1])) + (__expf(lg[2]) + __expf(lg[3]));
}

// ws layout (float units):
//   xw         [2][T][B][H] f32      @ 0       (131072)
//   featsB     [4096][32]   bf16     @ 131072  (65536)
//   W_hoT      [32000][32]  bf16     @ 196608  (512000)
//   stats_part [4096][20]   f32      @ 708608  (81920)

// Kernel 0: xw[dir][t][b][j] = b_ih[j] + emb[ix[t][b]] @ W[0:E, j]
__global__ __launch_bounds__(256) void xw_kernel(const int* __restrict__ ix,
                                                 const float* __restrict__ emb,
                                                 const float* __restrict__ W_lr,
                                                 const float* __restrict__ b_lr,
                                                 const float* __restrict__ W_rl,
                                                 const float* __restrict__ b_rl,
                                                 float* __restrict__ xw) {
    int idx = blockIdx.x * 256 + threadIdx.x;          // 131072 total
    int j = idx & 15;
    int b = (idx >> 4) & 31;
    int t = (idx >> 9) & 127;
    int dir = idx >> 16;
    const float* W    = dir ? W_rl : W_lr;
    const float* bias = dir ? b_rl : b_lr;
    int tok = ix[t * B_ + b];
    const float* er = emb + (long)tok * E_;
    float acc = bias[j];
#pragma unroll
    for (int e = 0; e < E_; ++e) acc += er[e] * W[e * H_ + j];
    xw[idx] = acc;
}

// Kernel 1 (fused): blocks 0..15 = scan chains (1 wave each, 4 chains/wave);
// blocks 16..515 = W_ho transpose to bf16.
__global__ __launch_bounds__(64) void scanwt_kernel(const float* __restrict__ xw,
                                                    const float* __restrict__ W_lr,
                                                    const float* __restrict__ W_rl,
                                                    const float* __restrict__ h0p,
                                                    const float* __restrict__ mask_lr,
                                                    const float* __restrict__ mask_rl,
                                                    __hip_bfloat16* __restrict__ featsB,
                                                    const float* __restrict__ W_ho,
                                                    __hip_bfloat16* __restrict__ W_hoT) {
    if (blockIdx.x >= 16) {
        int c = (blockIdx.x - 16) * 64 + threadIdx.x;   // 500*64 = 32000 exactly
        __hip_bfloat16 tmp[32];
#pragma unroll
        for (int k = 0; k < 32; ++k) tmp[k] = __float2bfloat16(W_ho[k * V_ + c]);
        short8* dst = (short8*)(W_hoT + c * 32);
        const short8* src = (const short8*)tmp;
#pragma unroll
        for (int q = 0; q < 4; ++q) dst[q] = src[q];
        return;
    }
    int lane = threadIdx.x;
    int dir = blockIdx.x >> 3;
    int j = lane & 15;
    int b = (blockIdx.x & 7) * 4 + (lane >> 4);
    int bi = b * 16 + j;
    int base = lane & 48;
    const float* W    = dir ? W_rl : W_lr;
    const float* mask = dir ? mask_rl : mask_lr;
    const float* xwd  = xw + dir * (T_ * B_ * H_);
    float Wh[16];
#pragma unroll
    for (int k = 0; k < 16; ++k) Wh[k] = W[(E_ + k) * H_ + j];
    float h = h0p[j];
    if (dir == 0) featsB[(0 * B_ + b) * 32 + j] = __float2bfloat16(h);
    else          featsB[((T_ - 1) * B_ + b) * 32 + 16 + j] = __float2bfloat16(h);

    float x0[4], m0[4], x1[4], m1[4];
#define LOADCH(XB, MB, CH)                                                 \
    _Pragma("unroll")                                                      \
    for (int u = 0; u < 4; ++u) {                                          \
        int t = (CH) * 4 + u;                                              \
        int tt = dir ? (T_ - 1 - t) : t;                                   \
        XB[u] = xwd[tt * (B_ * H_) + bi];                                  \
        MB[u] = mask[tt * (B_ * H_) + bi];                                 \
    }
#define STEPS(XB, MB, CH)                                                  \
    _Pragma("unroll")                                                      \
    for (int u = 0; u < 4; ++u) {                                          \
        int t = (CH) * 4 + u;                                              \
        float a0 = XB[u], a1 = 0.f, a2 = 0.f, a3 = 0.f;                    \
        _Pragma("unroll")                                                  \
        for (int k = 0; k < 16; k += 4) {                                  \
            a0 += __shfl(h, base + k,     64) * Wh[k];                     \
            a1 += __shfl(h, base + k + 1, 64) * Wh[k + 1];                 \
            a2 += __shfl(h, base + k + 2, 64) * Wh[k + 2];                 \
            a3 += __shfl(h, base + k + 3, 64) * Wh[k + 3];                 \
        }                                                                  \
        float ax = (a0 + a1) + (a2 + a3);                                  \
        float ex = __expf(2.f * ax);                                       \
        float th = 1.f - 2.f * __builtin_amdgcn_rcpf(ex + 1.f);            \
        float hn = th * MB[u];                                             \
        h = hn;                                                            \
        int p = dir ? (T_ - 2 - t) : (t + 1);                              \
        if (p >= 0 && p < T_)                                              \
            featsB[(p * B_ + b) * 32 + dir * 16 + j] = __float2bfloat16(hn); \
    }
    LOADCH(x0, m0, 0)
#pragma unroll 1
    for (int c = 0; c < 32; c += 2) {
        if (c + 1 < 32) { LOADCH(x1, m1, c + 1) }
        STEPS(x0, m0, c)
        if (c + 2 < 32) { LOADCH(x0, m0, c + 2) }
        STEPS(x1, m1, c + 1)
    }
#undef LOADCH
#undef STEPS
}

// MFMA (16x16x32, swapped: A = W-tile [16 cols x 32 k], B = feats):
//   lane L: p = L&15, kb = (L>>4)*8; D: lane holds row (L&15), cols c0+(L>>4)*4+{0..3}

#define LDA4(d0, d1, d2, d3, itv)                                          \
    d0 = *(const short8*)(WA + (cbase + (itv) * 64 +  0 + p) * 32 + kb);   \
    d1 = *(const short8*)(WA + (cbase + (itv) * 64 + 16 + p) * 32 + kb);   \
    d2 = *(const short8*)(WA + (cbase + (itv) * 64 + 32 + p) * 32 + kb);   \
    d3 = *(const short8*)(WA + (cbase + (itv) * 64 + 48 + p) * 32 + kb);
#define LDB4(d0, d1, d2, d3, itv)                                          \
    d0 = *(const f32x4*)(b_ho + cbase + (itv) * 64 +  0 + quad);           \
    d1 = *(const f32x4*)(b_ho + cbase + (itv) * 64 + 16 + quad);           \
    d2 = *(const f32x4*)(b_ho + cbase + (itv) * 64 + 32 + quad);           \
    d3 = *(const f32x4*)(b_ho + cbase + (itv) * 64 + 48 + quad);

// Kernel 2: per-row sum(exp(logit)). Wave = 32 rows (2 bfrags, 2 MFMAs/afrag)
// x one 1600-col segment (r8/r9 geometry — best measured). Depth-2 register
// pipeline on afrags+biases; bias enters via the MFMA C operand.
__global__ __launch_bounds__(256) void stats_kernel(const __hip_bfloat16* __restrict__ featsB,
                                                    const __hip_bfloat16* __restrict__ W_hoT,
                                                    const float* __restrict__ b_ho,
                                                    float* __restrict__ stats_part) {
    int wv = threadIdx.x >> 6, lane = threadIdx.x & 63;
    int rt = blockIdx.x * 4 + wv;        // 0..127 (32-row tiles)
    int seg = blockIdx.y;                // 0..19
    int row0 = rt * 32;
    int p = lane & 15, kb = (lane >> 4) * 8, quad = (lane >> 4) << 2;
    short8 bf0 = *(const short8*)((const short*)featsB + (row0 + p) * 32 + kb);
    short8 bf1 = *(const short8*)((const short*)featsB + (row0 + 16 + p) * 32 + kb);
    int cbase = seg * SEGW;
    const short* WA = (const short*)W_hoT;
    short8 pa0, pa1, pa2, pa3, pb0, pb1, pb2, pb3;
    f32x4  ba0, ba1, ba2, ba3, bb0, bb1, bb2, bb3;
    LDA4(pa0, pa1, pa2, pa3, 0)
    LDB4(ba0, ba1, ba2, ba3, 0)
    LDA4(pb0, pb1, pb2, pb3, 1)
    LDB4(bb0, bb1, bb2, bb3, 1)
    float ra = 0.f, rb = 0.f;
#define SBODY(c0, c1, c2, c3, d0, d1, d2, d3)                              \
    ra += expsum4(MFMA_BF16C(c0, bf0, d0));                                \
    rb += expsum4(MFMA_BF16C(c0, bf1, d0));                                \
    ra += expsum4(MFMA_BF16C(c1, bf0, d1));                                \
    rb += expsum4(MFMA_BF16C(c1, bf1, d1));                                \
    ra += expsum4(MFMA_BF16C(c2, bf0, d2));                                \
    rb += expsum4(MFMA_BF16C(c2, bf1, d2));                                \
    ra += expsum4(MFMA_BF16C(c3, bf0, d3));                                \
    rb += expsum4(MFMA_BF16C(c3, bf1, d3));
#pragma unroll 1
    for (int it = 0; it < NIT; it += 2) {
        short8 c0 = pa0, c1 = pa1, c2 = pa2, c3 = pa3;
        f32x4  d0 = ba0, d1 = ba1, d2 = ba2, d3 = ba3;
        if (it + 2 < NIT) { LDA4(pa0, pa1, pa2, pa3, it + 2) LDB4(ba0, ba1, ba2, ba3, it + 2) }
        SBODY(c0, c1, c2, c3, d0, d1, d2, d3)
        if (it + 1 < NIT) {
            short8 e0 = pb0, e1 = pb1, e2 = pb2, e3 = pb3;
            f32x4  f0 = bb0, f1 = bb1, f2 = bb2, f3 = bb3;
            if (it + 3 < NIT) { LDA4(pb0, pb1, pb2, pb3, it + 3) LDB4(bb0, bb1, bb2, bb3, it + 3) }
            SBODY(e0, e1, e2, e3, f0, f1, f2, f3)
        }
    }
#undef SBODY
    ra += __shfl_xor(ra, 16, 64);
    ra += __shfl_xor(ra, 32, 64);
    rb += __shfl_xor(rb, 16, 64);
    rb += __shfl_xor(rb, 32, 64);
    if (lane < 16) {
        stats_part[(row0 + lane) * NSEG + seg] = ra;
        stats_part[(row0 + 16 + lane) * NSEG + seg] = rb;
    }
}

// Kernel 3: out = logit - lse. lse from stats_part in-prologue; biases in LDS
// (C operand from LDS load); depth-2 afrag pipeline; staged LDS transpose ->
// 256 B contiguous NT stores.
__global__ __launch_bounds__(256) void out_kernel(const __hip_bfloat16* __restrict__ featsB,
                                                  const __hip_bfloat16* __restrict__ W_hoT,
                                                  const float* __restrict__ b_ho,
                                                  const float* __restrict__ stats_part,
                                                  float* __restrict__ out) {
    __shared__ float tile[4][16][68];
    __shared__ float bseg[SEGW];
    int wv = threadIdx.x >> 6, lane = threadIdx.x & 63;
    int rt = blockIdx.x * 4 + wv;        // 0..255
    int seg = blockIdx.y;                // 0..19
    int row0 = rt * 16;
    int p = lane & 15, kb = (lane >> 4) * 8, quad = (lane >> 4) << 2;
    int cbase = seg * SEGW;
    for (int i = threadIdx.x; i < SEGW / 4; i += 256)
        *(f32x4*)(bseg + i * 4) = *(const f32x4*)(b_ho + cbase + i * 4);
    // lse for this lane's row: 5 x f32x4 over the 20 partials
    const f32x4* sp4 = (const f32x4*)(stats_part + (row0 + p) * NSEG);
    f32x4 s4 = sp4[0] + sp4[1] + sp4[2] + sp4[3] + sp4[4];
    float ls = __logf((s4[0] + s4[1]) + (s4[2] + s4[3]));
    short8 bfrag = *(const short8*)((const short*)featsB + (row0 + p) * 32 + kb);
    const short* WA = (const short*)W_hoT;
    float* tw = &tile[wv][0][0];
    int rr = lane >> 4;             // 0..3
    int cc = (lane & 15) * 4;       // 0..60
    short8 pa0, pa1, pa2, pa3, pb0, pb1, pb2, pb3;
    LDA4(pa0, pa1, pa2, pa3, 0)
    LDA4(pb0, pb1, pb2, pb3, 1)
    __syncthreads();                // bseg ready
#define OBODY(itv, c0, c1, c2, c3)                                          \
    {                                                                       \
        int co = (itv) * 64;                                                \
        f32x4 b40 = *(const f32x4*)(bseg + co +  0 + quad);                 \
        f32x4 b41 = *(const f32x4*)(bseg + co + 16 + quad);                 \
        f32x4 b42 = *(const f32x4*)(bseg + co + 32 + quad);                 \
        f32x4 b43 = *(const f32x4*)(bseg + co + 48 + quad);                 \
        f32x4 lg0 = MFMA_BF16C(c0, bfrag, b40);                             \
        f32x4 lg1 = MFMA_BF16C(c1, bfrag, b41);                             \
        f32x4 lg2 = MFMA_BF16C(c2, bfrag, b42);                             \
        f32x4 lg3 = MFMA_BF16C(c3, bfrag, b43);                             \
        *(f32x4*)(tw + p * 68 +  0 + quad) = lg0 - ls;                      \
        *(f32x4*)(tw + p * 68 + 16 + quad) = lg1 - ls;                      \
        *(f32x4*)(tw + p * 68 + 32 + quad) = lg2 - ls;                      \
        *(f32x4*)(tw + p * 68 + 48 + quad) = lg3 - ls;                      \
        int c0g = cbase + co;                                               \
        _Pragma("unroll")                                                   \
        for (int sN = 0; sN < 4; ++sN) {                                    \
            int r = sN * 4 + rr;                                            \
            f32x4 v = *(const f32x4*)(tw + r * 68 + cc);                    \
            __builtin_nontemporal_store(v, (f32x4*)(out + (long)(row0 + r) * V_ + c0g + cc)); \
        }                                                                   \
    }
#pragma unroll 1
    for (int it = 0; it < NIT; it += 2) {
        short8 c0 = pa0, c1 = pa1, c2 = pa2, c3 = pa3;
        if (it + 2 < NIT) { LDA4(pa0, pa1, pa2, pa3, it + 2) }
        OBODY(it, c0, c1, c2, c3)
        if (it + 1 < NIT) {
            short8 e0 = pb0, e1 = pb1, e2 = pb2, e3 = pb3;
            if (it + 3 < NIT) { LDA4(pb0, pb1, pb2, pb3, it + 3) }
            OBODY(it + 1, e0, e1, e2, e3)
        }
    }
#undef OBODY
}

extern "C" void kernel_launch(void* const* d_in, const int* in_sizes, int n_in,
                              void* d_out, int out_size, void* d_ws, size_t ws_size,
                              hipStream_t stream) {
    const int*   ix      = (const int*)d_in[0];
    const float* emb     = (const float*)d_in[1];
    const float* W_lr    = (const float*)d_in[2];
    const float* b_lr    = (const float*)d_in[3];
    const float* W_rl    = (const float*)d_in[4];
    const float* b_rl    = (const float*)d_in[5];
    const float* W_ho    = (const float*)d_in[6];
    const float* b_ho    = (const float*)d_in[7];
    const float* h0      = (const float*)d_in[8];
    const float* mask_lr = (const float*)d_in[9];
    const float* mask_rl = (const float*)d_in[10];
    float* out = (float*)d_out;
    float* ws  = (float*)d_ws;

    float*           xw         = ws;                                   // 131072
    __hip_bfloat16*  featsB     = (__hip_bfloat16*)(ws + 131072);       // 65536
    __hip_bfloat16*  W_hoT      = (__hip_bfloat16*)(ws + 196608);       // 512000
    float*           stats_part = ws + 708608;                          // 81920

    xw_kernel<<<512, 256, 0, stream>>>(ix, emb, W_lr, b_lr, W_rl, b_rl, xw);
    scanwt_kernel<<<516, 64, 0, stream>>>(xw, W_lr, W_rl, h0, mask_lr, mask_rl,
                                          featsB, W_ho, W_hoT);
    stats_kernel<<<dim3(32, NSEG), 256, 0, stream>>>(featsB, W_hoT, b_ho, stats_part);
    out_kernel<<<dim3(64, NSEG), 256, 0, stream>>>(featsB, W_hoT, b_ho, stats_part, out);
}